// Round 10
// baseline (942.534 us; speedup 1.0000x reference)
//
#include <hip/hip_runtime.h>
#include <hip/hip_fp16.h>
#include <hip/hip_cooperative_groups.h>

namespace cg = cooperative_groups;

#define N_ROWS 65536
#define D_COLS 1024
#define M_ROWS 32768
#define HROWS  32768          // rows per LDS half-pass (128 KB f32)
#define NBLK   256            // 1 block per CU (cooperative co-residency)
#define NTHR   1024

using u32 = unsigned int;
using u16 = unsigned short;
typedef float f32x4 __attribute__((ext_vector_type(4)));
typedef int   i32x4 __attribute__((ext_vector_type(4)));

union SharedU {
    float acc[HROWS];                                      // 128 KB (phase 2)
    struct { u32 sidx[64][65]; float supd[64][65]; } p1;   // 33.3 KB (phase 1)
    struct { float sm[64][65]; float wmax[16]; } p3;       // 16.7 KB (phase 3)
};

__global__ __launch_bounds__(NTHR) void mega_k(
        const int* __restrict__ var, const float* __restrict__ var_scale,
        const int* __restrict__ idx, const float* __restrict__ upd,
        const float* __restrict__ scl,
        u32* __restrict__ packed, __half* __restrict__ sumT,
        float* __restrict__ outf, f32x4* __restrict__ y4,
        float* __restrict__ scale_out, u32* __restrict__ ws) {
    extern __shared__ char smem[];
    SharedU& S = *reinterpret_cast<SharedU*>(smem);
    cg::grid_group grid = cg::this_grid();
    const int bid = blockIdx.x, tid = threadIdx.x;

    if (bid == 0 && tid == 0) ws[0] = 0u;   // abs-max accumulator

    // ---- phase 1: transpose+pack  packed[j][i] = (u16)idx[i][j] | fp16(upd*scl)<<16 ----
    for (int tile = bid; tile < 8192; tile += NBLK) {
        const int j0 = (tile & 15) * 64, i0 = (tile >> 4) * 64;
        {
            const int rr = tid >> 4, c4 = tid & 15;
            const i32x4 iv = __builtin_nontemporal_load(
                (const i32x4*)(idx + (size_t)(i0 + rr) * D_COLS + j0) + c4);
            const f32x4 uv = __builtin_nontemporal_load(
                (const f32x4*)(upd + (size_t)(i0 + rr) * D_COLS + j0) + c4);
            S.p1.sidx[rr][c4 * 4 + 0] = (u32)iv.x;
            S.p1.sidx[rr][c4 * 4 + 1] = (u32)iv.y;
            S.p1.sidx[rr][c4 * 4 + 2] = (u32)iv.z;
            S.p1.sidx[rr][c4 * 4 + 3] = (u32)iv.w;
            S.p1.supd[rr][c4 * 4 + 0] = uv.x;
            S.p1.supd[rr][c4 * 4 + 1] = uv.y;
            S.p1.supd[rr][c4 * 4 + 2] = uv.z;
            S.p1.supd[rr][c4 * 4 + 3] = uv.w;
        }
        __syncthreads();
        {
            const int jj = tid >> 4, seg = tid & 15;
            const __half hs = __float2half(scl[j0 + jj]);   // exact fp16 scale
            u32 w[4];
            #pragma unroll
            for (int k = 0; k < 4; ++k) {
                const int r = seg * 4 + k;
                const __half hv = __hmul(__float2half(S.p1.supd[r][jj]), hs); // fp16 = ref
                w[k] = (S.p1.sidx[r][jj] & 0xffffu) |
                       ((u32)__half_as_ushort(hv) << 16);
            }
            *(uint4*)(packed + (size_t)(j0 + jj) * M_ROWS + i0 + seg * 4) =
                uint4{w[0], w[1], w[2], w[3]};
        }
        __syncthreads();
    }
    __threadfence();
    grid.sync();

    // ---- phase 2: per column, 2 half-passes: zero LDS -> LDS atomics -> fp16 write ----
    for (int j = bid; j < D_COLS; j += NBLK) {
        const i32x4* col4 = (const i32x4*)(packed + (size_t)j * M_ROWS);  // 8192 int4
        for (int h = 0; h < 2; ++h) {
            float4* a4 = (float4*)S.acc;
            for (int t = tid; t < HROWS / 4; t += NTHR) a4[t] = float4{0.f, 0.f, 0.f, 0.f};
            __syncthreads();
            #pragma unroll
            for (int k = 0; k < 8; ++k) {
                const i32x4 e = col4[k * NTHR + tid];
                const u32 ee[4] = {(u32)e.x, (u32)e.y, (u32)e.z, (u32)e.w};
                #pragma unroll
                for (int q = 0; q < 4; ++q) {
                    const int r = (int)(ee[q] & 0xffffu);
                    if ((r >> 15) == h)
                        atomicAdd(&S.acc[r & (HROWS - 1)],
                                  __half2float(__ushort_as_half((u16)(ee[q] >> 16))));
                }
            }
            __syncthreads();
            __half2* dst = (__half2*)(sumT + (size_t)j * N_ROWS + h * HROWS);
            for (int t = tid; t < HROWS / 2; t += NTHR)
                dst[t] = __floats2half2_rn(S.acc[2 * t], S.acc[2 * t + 1]);
            __syncthreads();
        }
    }
    __threadfence();
    grid.sync();

    // ---- phase 3: out = var*s + sumT^T (row-major coalesced) + fused abs-max ----
    const float s = var_scale[0];
    float m = 0.f;
    for (int tile = bid; tile < 16384; tile += NBLK) {
        const int r0 = (tile >> 4) * 64, j0 = (tile & 15) * 64;
        {
            const int jj = tid >> 4, seg = tid & 15;    // 4 halfs = 8B per thread
            const u32* p = (const u32*)(sumT + (size_t)(j0 + jj) * N_ROWS + r0 + seg * 4);
            const u32 w0 = p[0], w1 = p[1];
            const float2 fa = __half22float2(*(const __half2*)&w0);
            const float2 fb = __half22float2(*(const __half2*)&w1);
            S.p3.sm[seg * 4 + 0][jj] = fa.x;
            S.p3.sm[seg * 4 + 1][jj] = fa.y;
            S.p3.sm[seg * 4 + 2][jj] = fb.x;
            S.p3.sm[seg * 4 + 3][jj] = fb.y;
        }
        __syncthreads();
        {
            const int rr = tid >> 4, c4 = tid & 15;
            const i32x4 v = __builtin_nontemporal_load(
                (const i32x4*)(var + (size_t)(r0 + rr) * D_COLS + j0) + c4);
            float4 o;
            o.x = (float)v.x * s + S.p3.sm[rr][c4 * 4 + 0];
            o.y = (float)v.y * s + S.p3.sm[rr][c4 * 4 + 1];
            o.z = (float)v.z * s + S.p3.sm[rr][c4 * 4 + 2];
            o.w = (float)v.w * s + S.p3.sm[rr][c4 * 4 + 3];
            ((float4*)(outf + (size_t)(r0 + rr) * D_COLS + j0))[c4] = o;
            m = fmaxf(m, fmaxf(fmaxf(fabsf(o.x), fabsf(o.y)),
                               fmaxf(fabsf(o.z), fabsf(o.w))));
        }
        __syncthreads();
    }
    for (int off = 32; off; off >>= 1) m = fmaxf(m, __shfl_xor(m, off));
    if ((tid & 63) == 0) S.p3.wmax[tid >> 6] = m;
    __syncthreads();
    if (tid == 0) {
        #pragma unroll
        for (int w = 1; w < 16; ++w) m = fmaxf(m, S.p3.wmax[w]);
        atomicMax(ws, __float_as_uint(m));
    }
    __threadfence();
    grid.sync();

    // ---- phase 4: y = clip(rint(out * 127/max)) as f32 (nt store over dead scratch) ----
    const float mx = __uint_as_float(*(volatile u32*)ws);
    const float inv = 127.0f / mx;
    const int gid = bid * NTHR + tid;
    if (gid == 0) scale_out[0] = mx / 127.0f;
    const float4* o4 = (const float4*)outf;
    const int n4 = N_ROWS * D_COLS / 4;
    for (int i = gid; i < n4; i += NBLK * NTHR) {
        const float4 v = o4[i];
        f32x4 o;
        o.x = fminf(fmaxf(rintf(v.x * inv), -128.f), 127.f);
        o.y = fminf(fmaxf(rintf(v.y * inv), -128.f), 127.f);
        o.z = fminf(fmaxf(rintf(v.z * inv), -128.f), 127.f);
        o.w = fminf(fmaxf(rintf(v.w * inv), -128.f), 127.f);
        __builtin_nontemporal_store(o, &y4[i]);
    }
}

extern "C" void kernel_launch(void* const* d_in, const int* in_sizes, int n_in,
                              void* d_out, int out_size, void* d_ws, size_t ws_size,
                              hipStream_t stream) {
    const int*   var       = (const int*)d_in[0];     // int8 transported as int32
    const float* var_scale = (const float*)d_in[1];
    const int*   idx       = (const int*)d_in[2];
    const float* upd       = (const float*)d_in[3];   // fp16 transported as f32
    const float* scl       = (const float*)d_in[4];   // fp16 transported as f32

    float* y    = (float*)d_out;                      // y (f32) [N*D] = bytes 0..256MB
    float* outf = y + (size_t)N_ROWS * D_COLS;        // out (f32) [N*D] = 256..512MB
    float* scale_out = y + 2 * (size_t)N_ROWS * D_COLS;

    // scratch in the not-yet-written y region (dead before phase 4 writes y)
    u32*    packed = (u32*)y;                                   // 128 MB [D][M]
    __half* sumT   = (__half*)((char*)y + (size_t)134217728);   // 128 MB [D][N]
    f32x4*  y4     = (f32x4*)y;
    u32*    ws     = (u32*)d_ws;

    static_assert(sizeof(SharedU) == 131072, "LDS union must be 128KB");
    hipFuncSetAttribute((const void*)mega_k,
                        hipFuncAttributeMaxDynamicSharedMemorySize, 131072);

    void* args[] = {(void*)&var, (void*)&var_scale, (void*)&idx, (void*)&upd,
                    (void*)&scl, (void*)&packed, (void*)&sumT, (void*)&outf,
                    (void*)&y4, (void*)&scale_out, (void*)&ws};
    hipLaunchCooperativeKernel((const void*)mega_k, dim3(NBLK), dim3(NTHR),
                               args, 131072, stream);
}

// Round 12
// 574.456 us; speedup vs baseline: 1.6407x; 1.6407x over previous
//
#include <hip/hip_runtime.h>
#include <hip/hip_fp16.h>

#define N_ROWS 65536
#define D_COLS 1024
#define M_ROWS 32768
#define QROWS  16384   // rows per scatter pass (64KB f32 LDS, 2 blocks/CU)

using u32 = unsigned int;
using u16 = unsigned short;
typedef float f32x4 __attribute__((ext_vector_type(4)));   // native vecs for nontemporal
typedef int   i32x4 __attribute__((ext_vector_type(4)));

// ---- ws[0] = 0 (abs-max accumulator) ----
__global__ void init_ws_k(u32* ws) {
    if (threadIdx.x == 0 && blockIdx.x == 0) ws[0] = 0u;
}

// ---- 64x64-tile transpose: idx[M,D]->idxT[D,M] (u16), upd[M,D]*scl[j] -> updT[D,M] (fp16)
//      nt loads (single-use streams); normal stores (re-read by scatter, keep in L3). ----
__global__ __launch_bounds__(256) void t_idx_upd_k(const int* __restrict__ idx,
                                                   const float* __restrict__ upd,
                                                   const float* __restrict__ scl,
                                                   u16* __restrict__ idxT,
                                                   __half* __restrict__ updT) {
    __shared__ u32   sidx[64][65];
    __shared__ float supd[64][65];
    const int j0 = (int)(blockIdx.x & 15) * 64;   // 16 j-tiles
    const int i0 = (int)(blockIdx.x >> 4) * 64;   // 512 i-tiles
    const int t = threadIdx.x;

    {
        const int rr = t >> 2, c4 = t & 3;
        const int*   ip = idx + (size_t)(i0 + rr) * D_COLS + j0;
        const float* up = upd + (size_t)(i0 + rr) * D_COLS + j0;
        #pragma unroll
        for (int cq = 0; cq < 4; ++cq) {
            const int jc = cq * 16 + c4 * 4;
            const i32x4 iv = __builtin_nontemporal_load((const i32x4*)(ip + jc));
            const f32x4 uv = __builtin_nontemporal_load((const f32x4*)(up + jc));
            sidx[rr][jc] = (u32)iv.x; sidx[rr][jc+1] = (u32)iv.y;
            sidx[rr][jc+2] = (u32)iv.z; sidx[rr][jc+3] = (u32)iv.w;
            supd[rr][jc] = uv.x; supd[rr][jc+1] = uv.y;
            supd[rr][jc+2] = uv.z; supd[rr][jc+3] = uv.w;
        }
    }
    __syncthreads();

    {
        const int jj = t >> 2, seg = t & 3;
        const __half hs = __float2half(scl[j0 + jj]);   // exact fp16 scale
        u32 wi[8], wh[8];
        #pragma unroll
        for (int p = 0; p < 8; ++p) {
            const int r = seg * 16 + 2 * p;
            const u32 a = sidx[r][jj] & 0xffffu, b = sidx[r + 1][jj] & 0xffffu;
            wi[p] = a | (b << 16);
            const __half2 h2 = __halves2half2(__hmul(__float2half(supd[r][jj]), hs),
                                              __hmul(__float2half(supd[r + 1][jj]), hs));
            wh[p] = *reinterpret_cast<const u32*>(&h2);
        }
        u16* di = idxT + (size_t)(j0 + jj) * M_ROWS + i0 + seg * 16;
        __half* dh = updT + (size_t)(j0 + jj) * M_ROWS + i0 + seg * 16;
        ((uint4*)di)[0] = uint4{wi[0], wi[1], wi[2], wi[3]};
        ((uint4*)di)[1] = uint4{wi[4], wi[5], wi[6], wi[7]};
        ((uint4*)dh)[0] = uint4{wh[0], wh[1], wh[2], wh[3]};
        ((uint4*)dh)[1] = uint4{wh[4], wh[5], wh[6], wh[7]};
    }
}

// ---- per (column j, quarter h): zero 64KB LDS f32 acc, scan column's updates,
//      LDS-atomic accumulate own quarter, dense fp16 write to sumT[D][N].
//      1024 thr + 64KB -> 2 blocks/CU = 2048 thr/CU (100% occupancy).
//      XCD swizzle co-schedules the 4 quarters of each column on one XCD (L2 reuse). ----
__global__ __launch_bounds__(1024) void scatter_q_k(const u16* __restrict__ idxT,
                                                    const __half* __restrict__ updT,
                                                    __half* __restrict__ sumT) {
    __shared__ float acc[QROWS];                  // 64 KB
    const int bid = (blockIdx.x & 7) * 512 + (blockIdx.x >> 3);  // bijective, 4096%8==0
    const int j = bid >> 2;                       // column 0..1023
    const int h = bid & 3;                        // row quarter
    const int tid = threadIdx.x;

    float4* acc4 = (float4*)acc;
    for (int t = tid; t < QROWS / 4; t += 1024) acc4[t] = float4{0.f, 0.f, 0.f, 0.f};

    const int4* ip4 = (const int4*)(idxT + (size_t)j * M_ROWS);  // 4096 int4 (8 u16 each)
    const int4* up4 = (const int4*)(updT + (size_t)j * M_ROWS);
    __syncthreads();

    #pragma unroll
    for (int k = 0; k < 4; ++k) {
        const int t = k * 1024 + tid;
        const int4 iv = ip4[t];
        const int4 uv = up4[t];
        const u32 iw[4] = {(u32)iv.x, (u32)iv.y, (u32)iv.z, (u32)iv.w};
        const u32 uw[4] = {(u32)uv.x, (u32)uv.y, (u32)uv.z, (u32)uv.w};
        #pragma unroll
        for (int e = 0; e < 4; ++e) {
            const int r0 = iw[e] & 0xffff, r1 = iw[e] >> 16;
            const __half2 h2 = *reinterpret_cast<const __half2*>(&uw[e]);
            if ((r0 >> 14) == h) atomicAdd(&acc[r0 & (QROWS - 1)], __half2float(__low2half(h2)));
            if ((r1 >> 14) == h) atomicAdd(&acc[r1 & (QROWS - 1)], __half2float(__high2half(h2)));
        }
    }
    __syncthreads();

    __half2* dst = (__half2*)(sumT + (size_t)j * N_ROWS + h * QROWS);
    for (int t = tid; t < QROWS / 2; t += 1024)
        dst[t] = __floats2half2_rn(acc[2 * t], acc[2 * t + 1]);
}

// ---- 64x64 tiles: out = var*s + sumT^T; var via nt loads (single-use);
//      out via normal stores (quant re-reads from L3); fused abs-max. ----
__global__ __launch_bounds__(256) void finalize_k(const int* __restrict__ var,
                                                  const __half* __restrict__ sumT,
                                                  const float* __restrict__ var_scale,
                                                  float* __restrict__ outf,
                                                  u32* __restrict__ ws) {
    __shared__ float sm[64][65];
    __shared__ float wmax[4];
    const int r0 = (int)(blockIdx.x >> 4) * 64;   // 1024 row-tiles
    const int j0 = (int)(blockIdx.x & 15) * 64;   // 16 col-tiles
    const int tid = threadIdx.x;
    const float s = var_scale[0];

    {
        const int jj = tid >> 2, seg = tid & 3;
        const __half* colp = sumT + (size_t)(j0 + jj) * N_ROWS + r0 + seg * 16;
        #pragma unroll
        for (int q = 0; q < 2; ++q) {
            const uint4 w = ((const uint4*)colp)[q];
            const u32 wv[4] = {w.x, w.y, w.z, w.w};
            #pragma unroll
            for (int i = 0; i < 4; ++i) {
                const __half2 hh = *reinterpret_cast<const __half2*>(&wv[i]);
                const float2 f = __half22float2(hh);
                const int rr = seg * 16 + q * 8 + i * 2;
                sm[rr][jj] = f.x;
                sm[rr + 1][jj] = f.y;
            }
        }
    }
    __syncthreads();

    float m = 0.f;
    #pragma unroll
    for (int k = 0; k < 4; ++k) {
        const int l = k * 256 + tid;              // 0..1023 int4 units
        const int rr = l >> 4, c4 = l & 15;
        const i32x4 v = __builtin_nontemporal_load(
            (const i32x4*)(var + (size_t)(r0 + rr) * D_COLS + j0) + c4);
        float4 o;
        o.x = (float)v.x * s + sm[rr][c4 * 4 + 0];
        o.y = (float)v.y * s + sm[rr][c4 * 4 + 1];
        o.z = (float)v.z * s + sm[rr][c4 * 4 + 2];
        o.w = (float)v.w * s + sm[rr][c4 * 4 + 3];
        ((float4*)(outf + (size_t)(r0 + rr) * D_COLS + j0))[c4] = o;
        m = fmaxf(m, fmaxf(fmaxf(fabsf(o.x), fabsf(o.y)),
                           fmaxf(fabsf(o.z), fabsf(o.w))));
    }
    for (int off = 32; off; off >>= 1) m = fmaxf(m, __shfl_xor(m, off));
    if ((tid & 63) == 0) wmax[tid >> 6] = m;
    __syncthreads();
    if (tid == 0) {
        m = fmaxf(fmaxf(wmax[0], wmax[1]), fmaxf(wmax[2], wmax[3]));
        atomicMax(ws, __float_as_uint(m));
    }
}

// ---- y = clip(rint(out * 127/max), -128, 127) stored as f32; write scale ----
__global__ __launch_bounds__(256) void quant_k(const float4* __restrict__ outf4,
                                               f32x4* __restrict__ y4,
                                               const u32* __restrict__ ws,
                                               float* __restrict__ scale_out, int n4) {
    const float mx = __uint_as_float(ws[0]);
    const float inv = 127.0f / mx;
    int gid = blockIdx.x * 256 + threadIdx.x;
    if (gid == 0) scale_out[0] = mx / 127.0f;
    const int stride = gridDim.x * 256;
    for (int i = gid; i < n4; i += stride) {
        float4 v = outf4[i];
        f32x4 o;
        o.x = fminf(fmaxf(rintf(v.x * inv), -128.f), 127.f);
        o.y = fminf(fmaxf(rintf(v.y * inv), -128.f), 127.f);
        o.z = fminf(fmaxf(rintf(v.z * inv), -128.f), 127.f);
        o.w = fminf(fmaxf(rintf(v.w * inv), -128.f), 127.f);
        __builtin_nontemporal_store(o, &y4[i]);   // y never re-read
    }
}

extern "C" void kernel_launch(void* const* d_in, const int* in_sizes, int n_in,
                              void* d_out, int out_size, void* d_ws, size_t ws_size,
                              hipStream_t stream) {
    const int*   var       = (const int*)d_in[0];     // int8 transported as int32
    const float* var_scale = (const float*)d_in[1];
    const int*   idx       = (const int*)d_in[2];
    const float* upd       = (const float*)d_in[3];   // fp16 transported as f32
    const float* scl       = (const float*)d_in[4];   // fp16 transported as f32

    float* y    = (float*)d_out;                      // y (f32) [N*D]
    float* outf = y + (size_t)N_ROWS * D_COLS;        // out (f32) [N*D]
    float* scale_out = y + 2 * (size_t)N_ROWS * D_COLS;

    // scratch packed into the (not-yet-written) y region: exactly 256 MB
    char* scratch = (char*)y;
    u16*    idxT = (u16*)scratch;                               // 64 MB
    __half* updT = (__half*)(scratch + (size_t)67108864);       // 64 MB
    __half* sumT = (__half*)(scratch + (size_t)134217728);      // 128 MB
    u32* ws = (u32*)d_ws;

    const int n4 = N_ROWS * D_COLS / 4;

    init_ws_k<<<1, 64, 0, stream>>>(ws);
    t_idx_upd_k<<<8192, 256, 0, stream>>>(idx, upd, scl, idxT, updT);
    scatter_q_k<<<4096, 1024, 0, stream>>>(idxT, updT, sumT);
    finalize_k<<<16384, 256, 0, stream>>>(var, sumT, var_scale, outf, ws);
    quant_k<<<4096, 256, 0, stream>>>((const float4*)outf, (f32x4*)y, ws, scale_out, n4);
}